// Round 1
// baseline (68.071 us; speedup 1.0000x reference)
//
#include <hip/hip_runtime.h>

#define NB 4
#define LL 8192
#define DD 1024
#define CHUNK 64
#define NT (LL / CHUNK)   // 128 tiles per batch
#define EPSV 1e-4f

// ---------------- K1: mask dtype detect + cumsum idx + clipped p ----------------
__global__ __launch_bounds__(1024) void k_prep(const void* __restrict__ mask_raw,
                                               const float* __restrict__ bprob,
                                               int* __restrict__ idx,
                                               float* __restrict__ p_out) {
    const int b = blockIdx.x;
    const int tid = threadIdx.x;
    __shared__ int s_viol;
    __shared__ int s_sums[1024];
    if (tid == 0) s_viol = 0;
    __syncthreads();

    // Detect mask storage: int32 (little-endian [0/1,0,0,0] pattern) vs uint8.
    // Check first 1024 int32 groups (4 KB; both layouts have >= 32 KB).
    {
        unsigned int w = ((const unsigned int*)mask_raw)[tid];
        if ((w & 0xFFFFFF00u) != 0u || (w & 0xFFu) > 1u) atomicOr(&s_viol, 1);
    }
    __syncthreads();
    const bool is_int = (s_viol == 0);

    const int base = b * LL + tid * 8;
    int m[8];
    if (is_int) {
        const int* mi = (const int*)mask_raw;
        #pragma unroll
        for (int k = 0; k < 8; ++k) m[k] = mi[base + k];
    } else {
        const unsigned char* mb = (const unsigned char*)mask_raw;
        #pragma unroll
        for (int k = 0; k < 8; ++k) m[k] = (int)mb[base + k];
    }
    int c[8];
    int s = 0;
    #pragma unroll
    for (int k = 0; k < 8; ++k) { s += m[k]; c[k] = s; }
    s_sums[tid] = s;
    __syncthreads();
    // Hillis-Steele inclusive scan over 1024 thread sums
    for (int off = 1; off < 1024; off <<= 1) {
        int v = s_sums[tid];
        int add = (tid >= off) ? s_sums[tid - off] : 0;
        __syncthreads();
        s_sums[tid] = v + add;
        __syncthreads();
    }
    const int excl = (tid > 0) ? s_sums[tid - 1] : 0;
    #pragma unroll
    for (int k = 0; k < 8; ++k) idx[base + k] = excl + c[k] - 1;

    #pragma unroll
    for (int k = 0; k < 8; ++k) {
        int l = tid * 8 + k;
        float v = bprob[((size_t)(b * LL + l)) * 2 + 1];
        v = fminf(fmaxf(v, EPSV), 1.0f - EPSV);
        if (l == 0) v = 1.0f;
        p_out[b * LL + l] = v;
    }
}

// ---------------- K2: per-tile affine aggregate (A = prod a, Bvec = local scan end) ----
__global__ __launch_bounds__(1024) void k_tile_agg(const float* __restrict__ hid,
                                                   const int* __restrict__ idx,
                                                   const float* __restrict__ p_ws,
                                                   float* __restrict__ A,
                                                   float* __restrict__ Bvec) {
    const int blk = blockIdx.x;            // b*NT + tile
    const int b = blk / NT, tile = blk % NT;
    const int d = threadIdx.x;
    __shared__ int s_idx[CHUNK];
    __shared__ float s_p[CHUNK];
    const int l0 = tile * CHUNK;
    if (d < CHUNK) {
        s_idx[d] = idx[b * LL + l0 + d];
        s_p[d]  = p_ws[b * LL + l0 + d];
    }
    __syncthreads();
    float prev = 0.f, cumA = 1.f;
    const float* hb = hid + (size_t)b * LL * DD + d;
    #pragma unroll 4
    for (int t = 0; t < CHUNK; ++t) {
        float p = s_p[t];
        float x = hb[(size_t)s_idx[t] * DD];
        prev = fmaf(p, x, (1.f - p) * prev);
        cumA *= (1.f - p);
    }
    Bvec[(size_t)blk * DD + d] = prev;
    if (d == 0) A[blk] = cumA;
}

// ---------------- K3: scan tile aggregates -> exclusive carry per (b,tile,d) --------
__global__ __launch_bounds__(256) void k_carry(const float* __restrict__ A,
                                               const float* __restrict__ Bvec,
                                               float* __restrict__ carry) {
    const int gid = blockIdx.x * 256 + threadIdx.x;  // NB*DD threads
    const int b = gid >> 10, d = gid & 1023;
    float c = 0.f;
    for (int j = 0; j < NT; ++j) {
        size_t o = ((size_t)(b * NT + j)) * DD + d;
        carry[o] = c;
        c = A[b * NT + j] * c + Bvec[o];
    }
}

// ---------------- K4: final scan seeded with carry, write out -----------------------
__global__ __launch_bounds__(1024) void k_final(const float* __restrict__ hid,
                                                const int* __restrict__ idx,
                                                const float* __restrict__ p_ws,
                                                const float* __restrict__ carry,
                                                float* __restrict__ out) {
    const int blk = blockIdx.x;
    const int b = blk / NT, tile = blk % NT;
    const int d = threadIdx.x;
    __shared__ int s_idx[CHUNK];
    __shared__ float s_p[CHUNK];
    const int l0 = tile * CHUNK;
    if (d < CHUNK) {
        s_idx[d] = idx[b * LL + l0 + d];
        s_p[d]  = p_ws[b * LL + l0 + d];
    }
    __syncthreads();
    float prev = carry[(size_t)blk * DD + d];
    const float* hb = hid + (size_t)b * LL * DD + d;
    float* ob = out + ((size_t)b * LL + l0) * DD + d;
    #pragma unroll 4
    for (int t = 0; t < CHUNK; ++t) {
        float p = s_p[t];
        float x = hb[(size_t)s_idx[t] * DD];
        prev = fmaf(p, x, (1.f - p) * prev);
        ob[(size_t)t * DD] = prev;
    }
}

extern "C" void kernel_launch(void* const* d_in, const int* in_sizes, int n_in,
                              void* d_out, int out_size, void* d_ws, size_t ws_size,
                              hipStream_t stream) {
    const float* hid   = (const float*)d_in[0];
    const void*  mask  = d_in[1];
    const float* bprob = (const float*)d_in[2];
    float* out = (float*)d_out;

    char* ws = (char*)d_ws;
    int*   idx   = (int*)(ws);                                   // NB*LL*4   = 128 KB
    float* p_ws  = (float*)(ws + 131072);                        // NB*LL*4   = 128 KB
    float* A     = (float*)(ws + 262144);                        // NB*NT*4   =   2 KB
    float* Bvec  = (float*)(ws + 264192);                        // NB*NT*DD*4 = 2 MB
    float* carry = (float*)(ws + 264192 + 2097152);              // NB*NT*DD*4 = 2 MB

    k_prep<<<NB, 1024, 0, stream>>>(mask, bprob, idx, p_ws);
    k_tile_agg<<<NB * NT, 1024, 0, stream>>>(hid, idx, p_ws, A, Bvec);
    k_carry<<<(NB * DD) / 256, 256, 0, stream>>>(A, Bvec, carry);
    k_final<<<NB * NT, 1024, 0, stream>>>(hid, idx, p_ws, carry, out);
}